// Round 2
// baseline (833.473 us; speedup 1.0000x reference)
//
#include <hip/hip_runtime.h>

#define N_NODES 100000
#define N_EDGES 3200000
#define N_GRAPHS 1000
#define NB_SCAN ((N_NODES + 255) / 256)   // 391 scan blocks

// ---------------- workspace layout (element offsets, 4B units) --------------
// deg  : int  [N]      @ 0      incoming real-edge count (self-loop excluded)
// row  : int  [N]      @ N      CSR row starts (exclusive scan of deg)
// cur  : int  [N]      @ 2N     fill cursors (init = row)
// exs  : int  [N]      @ 3N     per-block exclusive scan partials
// dinv : float[N]      @ 4N     rsqrt(deg+1)
// xp   : float[4N]     @ 5N     x * dinv  (pre-scaled L1 features)
// t2p  : float[32N]    @ 9N     (h1@W2) * dinv
// agg2 : float[32N]    @ 41N
// t3p  : float[16N]    @ 73N    (h2@W3) * dinv
// agg3 : float[16N]    @ 89N
// csr  : int  [E]      @ 105N   source node per edge, grouped by dst
// bsum : int  [1024]   @ 105N+E
// boff : int  [1024]   @ 105N+E+1024
// gsum : float[G]      @ 105N+E+2048
// gcnt : int  [G]      @ 105N+E+2048+G
// total ≈ 13.7M elements ≈ 55 MB

__global__ void k_zero(int* __restrict__ deg, float* __restrict__ gsum,
                       int* __restrict__ gcnt) {
    int i = blockIdx.x * blockDim.x + threadIdx.x;
    if (i < N_NODES) deg[i] = 0;
    if (i < N_GRAPHS) { gsum[i] = 0.0f; gcnt[i] = 0; }
}

__global__ void k_degree(const int* __restrict__ dst, int* __restrict__ deg) {
    int e = blockIdx.x * blockDim.x + threadIdx.x;
    if (e < N_EDGES) atomicAdd(&deg[dst[e]], 1);
}

// per-block inclusive scan -> exclusive partials + block totals
__global__ void k_scan1(const int* __restrict__ deg, int* __restrict__ exs,
                        int* __restrict__ bsum) {
    __shared__ int s[256];
    int i = blockIdx.x * 256 + threadIdx.x;
    int v = (i < N_NODES) ? deg[i] : 0;
    s[threadIdx.x] = v;
    __syncthreads();
    for (int off = 1; off < 256; off <<= 1) {
        int t = (threadIdx.x >= off) ? s[threadIdx.x - off] : 0;
        __syncthreads();
        s[threadIdx.x] += t;
        __syncthreads();
    }
    if (i < N_NODES) exs[i] = s[threadIdx.x] - v;   // exclusive within block
    if (threadIdx.x == 255) bsum[blockIdx.x] = s[255];
}

// single block scans the 391 block totals -> exclusive block offsets
__global__ void k_scan2(const int* __restrict__ bsum, int* __restrict__ boff) {
    __shared__ int s[512];
    int t = threadIdx.x;
    int v = (t < NB_SCAN) ? bsum[t] : 0;
    s[t] = v;
    __syncthreads();
    for (int off = 1; off < 512; off <<= 1) {
        int u = (t >= off) ? s[t - off] : 0;
        __syncthreads();
        s[t] += u;
        __syncthreads();
    }
    if (t < NB_SCAN) boff[t] = s[t] - v;
}

__global__ void k_scan3(const int* __restrict__ exs, const int* __restrict__ boff,
                        int* __restrict__ row, int* __restrict__ cur) {
    int i = blockIdx.x * 256 + threadIdx.x;
    if (i >= N_NODES) return;
    int r = exs[i] + boff[blockIdx.x];
    row[i] = r;
    cur[i] = r;
}

// scatter edge sources into CSR slots (int atomics on cursors only)
__global__ void k_fill(const int* __restrict__ src, const int* __restrict__ dst,
                       int* __restrict__ cur, int* __restrict__ csr) {
    int e = blockIdx.x * blockDim.x + threadIdx.x;
    if (e >= N_EDGES) return;
    int p = atomicAdd(&cur[dst[e]], 1);
    csr[p] = src[e];
}

__global__ void k_prep(const float* __restrict__ x, const int* __restrict__ deg,
                       float* __restrict__ dinv, float* __restrict__ xp) {
    int n = blockIdx.x * blockDim.x + threadIdx.x;
    if (n >= N_NODES) return;
    float di = rsqrtf((float)(deg[n] + 1));        // +1 self-loop
    dinv[n] = di;
    float4 v = reinterpret_cast<const float4*>(x)[n];
    v.x *= di; v.y *= di; v.z *= di; v.w *= di;
    reinterpret_cast<float4*>(xp)[n] = v;
}

// fused: L1 gather (4 floats over in-edges + self) -> *dinv -> @W1+b1 -> relu
//        -> @W2 -> *dinv -> t2p.   h1 [N,64] and agg1 never materialized.
__global__ __launch_bounds__(256) void k_l1(
    const float* __restrict__ xp, const int* __restrict__ row,
    const int* __restrict__ deg, const int* __restrict__ csr,
    const float* __restrict__ dinv,
    const float* __restrict__ W1, const float* __restrict__ b1,
    const float* __restrict__ W2, float* __restrict__ t2p) {
    __shared__ float sW1[4 * 64], sb1[64], sW2[64 * 32];
    sW1[threadIdx.x] = W1[threadIdx.x];
    if (threadIdx.x < 64) sb1[threadIdx.x] = b1[threadIdx.x];
    for (int i = threadIdx.x; i < 64 * 32; i += 256) sW2[i] = W2[i];
    __syncthreads();

    int n = blockIdx.x * 256 + threadIdx.x;
    if (n >= N_NODES) return;
    float4 a4 = reinterpret_cast<const float4*>(xp)[n];    // self-loop term
    int r = row[n], dg = deg[n];
    for (int j = 0; j < dg; ++j) {
        int s = csr[r + j];
        float4 v = reinterpret_cast<const float4*>(xp)[s];
        a4.x += v.x; a4.y += v.y; a4.z += v.z; a4.w += v.w;
    }
    float di = dinv[n];
    float a[4] = {a4.x * di, a4.y * di, a4.z * di, a4.w * di};

    float t[32];
#pragma unroll
    for (int k = 0; k < 32; ++k) t[k] = 0.0f;
    for (int j = 0; j < 64; ++j) {
        float h = sb1[j];
#pragma unroll
        for (int i = 0; i < 4; ++i) h += a[i] * sW1[i * 64 + j];
        h = fmaxf(h, 0.0f);                                 // relu(L1)
#pragma unroll
        for (int k = 0; k < 32; ++k) t[k] += h * sW2[j * 32 + k];
    }
    float4* o = reinterpret_cast<float4*>(t2p + (size_t)n * 32);
#pragma unroll
    for (int q = 0; q < 8; ++q)
        o[q] = make_float4(t[q*4+0]*di, t[q*4+1]*di, t[q*4+2]*di, t[q*4+3]*di);
}

// L2 gather: 32 lanes per node; per edge one coalesced 128B line of t2p.
__global__ void k_g2(const float* __restrict__ t2p, const int* __restrict__ row,
                     const int* __restrict__ deg, const int* __restrict__ csr,
                     float* __restrict__ agg2) {
    unsigned gid = blockIdx.x * 256u + threadIdx.x;
    unsigned n = gid >> 5; int f = gid & 31;
    if (n >= N_NODES) return;
    int r = row[n], dg = deg[n];
    float acc = t2p[(size_t)n * 32 + f];                    // self-loop term
    for (int j = 0; j < dg; ++j) {
        int s = csr[r + j];                                 // wave-broadcast
        acc += t2p[(size_t)s * 32 + f];
    }
    agg2[(size_t)n * 32 + f] = acc;
}

// finish L2 (relu(agg2*dinv + b2)), t3 = h2@W3, pre-scale, write t3p
__global__ __launch_bounds__(256) void k_dense2(
    const float* __restrict__ agg2, const float* __restrict__ dinv,
    const float* __restrict__ b2, const float* __restrict__ W3,
    float* __restrict__ t3p) {
    __shared__ float sb2[32], sW3[32 * 16];
    if (threadIdx.x < 32) sb2[threadIdx.x] = b2[threadIdx.x];
    for (int i = threadIdx.x; i < 32 * 16; i += 256) sW3[i] = W3[i];
    __syncthreads();

    int n = blockIdx.x * 256 + threadIdx.x;
    if (n >= N_NODES) return;
    float di = dinv[n];
    float h[32];
    const float4* in = reinterpret_cast<const float4*>(agg2 + (size_t)n * 32);
#pragma unroll
    for (int q = 0; q < 8; ++q) {
        float4 v = in[q];
        h[q*4+0] = fmaxf(v.x * di + sb2[q*4+0], 0.0f);
        h[q*4+1] = fmaxf(v.y * di + sb2[q*4+1], 0.0f);
        h[q*4+2] = fmaxf(v.z * di + sb2[q*4+2], 0.0f);
        h[q*4+3] = fmaxf(v.w * di + sb2[q*4+3], 0.0f);
    }
    float t[16];
#pragma unroll
    for (int k = 0; k < 16; ++k) t[k] = 0.0f;
    for (int j = 0; j < 32; ++j) {
#pragma unroll
        for (int k = 0; k < 16; ++k) t[k] += h[j] * sW3[j * 16 + k];
    }
    float4* o = reinterpret_cast<float4*>(t3p + (size_t)n * 16);
#pragma unroll
    for (int q = 0; q < 4; ++q)
        o[q] = make_float4(t[q*4+0]*di, t[q*4+1]*di, t[q*4+2]*di, t[q*4+3]*di);
}

// L3 gather: 16 lanes per node (64B line per edge)
__global__ void k_g3(const float* __restrict__ t3p, const int* __restrict__ row,
                     const int* __restrict__ deg, const int* __restrict__ csr,
                     float* __restrict__ agg3) {
    unsigned gid = blockIdx.x * 256u + threadIdx.x;
    unsigned n = gid >> 4; int f = gid & 15;
    if (n >= N_NODES) return;
    int r = row[n], dg = deg[n];
    float acc = t3p[(size_t)n * 16 + f];                    // self-loop term
    for (int j = 0; j < dg; ++j) {
        int s = csr[r + j];
        acc += t3p[(size_t)s * 16 + f];
    }
    agg3[(size_t)n * 16 + f] = acc;
}

// finish L3 (+b3, no relu), fuse 16->1 head dot and mean-pool segment-sum
__global__ void k_pool(const float* __restrict__ agg3, const float* __restrict__ dinv,
                       const float* __restrict__ b3, const float* __restrict__ Wl,
                       const int* __restrict__ batch,
                       float* __restrict__ gsum, int* __restrict__ gcnt) {
    int n = blockIdx.x * blockDim.x + threadIdx.x;
    if (n >= N_NODES) return;
    float di = dinv[n];
    const float4* in = reinterpret_cast<const float4*>(agg3 + (size_t)n * 16);
    float s = 0.0f;
#pragma unroll
    for (int q = 0; q < 4; ++q) {
        float4 v = in[q];
        s += (v.x * di + b3[q*4+0]) * Wl[q*4+0];
        s += (v.y * di + b3[q*4+1]) * Wl[q*4+1];
        s += (v.z * di + b3[q*4+2]) * Wl[q*4+2];
        s += (v.w * di + b3[q*4+3]) * Wl[q*4+3];
    }
    int g = batch[n];
    atomicAdd(&gsum[g], s);
    atomicAdd(&gcnt[g], 1);
}

__global__ void k_head(const float* __restrict__ gsum, const int* __restrict__ gcnt,
                       const float* __restrict__ bl, float* __restrict__ out) {
    int g = blockIdx.x * blockDim.x + threadIdx.x;
    if (g >= N_GRAPHS) return;
    float c = fmaxf((float)gcnt[g], 1.0f);
    out[g] = fmaxf(gsum[g] / c + bl[0], 0.0f);
}

extern "C" void kernel_launch(void* const* d_in, const int* in_sizes, int n_in,
                              void* d_out, int out_size, void* d_ws, size_t ws_size,
                              hipStream_t stream) {
    const float* x  = (const float*)d_in[0];
    const float* W1 = (const float*)d_in[1];
    const float* b1 = (const float*)d_in[2];
    const float* W2 = (const float*)d_in[3];
    const float* b2 = (const float*)d_in[4];
    const float* W3 = (const float*)d_in[5];
    const float* b3 = (const float*)d_in[6];
    const float* Wl = (const float*)d_in[7];
    const float* bl = (const float*)d_in[8];
    const int*   ei = (const int*)d_in[9];        // [2, E] row-major
    const int* batch = (const int*)d_in[10];
    const int* src = ei;
    const int* dst = ei + N_EDGES;
    float* out = (float*)d_out;

    const size_t N = N_NODES, E = N_EDGES, G = N_GRAPHS;
    char* ws = (char*)d_ws;
    int*   deg  = (int*)  (ws);
    int*   rowp = (int*)  (ws + 4 * (N));
    int*   cur  = (int*)  (ws + 4 * (2 * N));
    int*   exs  = (int*)  (ws + 4 * (3 * N));
    float* dinv = (float*)(ws + 4 * (4 * N));
    float* xp   = (float*)(ws + 4 * (5 * N));
    float* t2p  = (float*)(ws + 4 * (9 * N));
    float* agg2 = (float*)(ws + 4 * (41 * N));
    float* t3p  = (float*)(ws + 4 * (73 * N));
    float* agg3 = (float*)(ws + 4 * (89 * N));
    int*   csr  = (int*)  (ws + 4 * (105 * N));
    int*   bsum = (int*)  (ws + 4 * (105 * N + E));
    int*   boff = (int*)  (ws + 4 * (105 * N + E + 1024));
    float* gsum = (float*)(ws + 4 * (105 * N + E + 2048));
    int*   gcnt = (int*)  (ws + 4 * (105 * N + E + 2048 + G));

    const int B = 256;
    const int gN = (N_NODES + B - 1) / B;          // 391
    const int gE = (N_EDGES + B - 1) / B;          // 12500

    k_zero  <<<gN, B, 0, stream>>>(deg, gsum, gcnt);
    k_degree<<<gE, B, 0, stream>>>(dst, deg);
    k_scan1 <<<gN, B, 0, stream>>>(deg, exs, bsum);
    k_scan2 <<<1, 512, 0, stream>>>(bsum, boff);
    k_scan3 <<<gN, B, 0, stream>>>(exs, boff, rowp, cur);
    k_fill  <<<gE, B, 0, stream>>>(src, dst, cur, csr);
    k_prep  <<<gN, B, 0, stream>>>(x, deg, dinv, xp);
    k_l1    <<<gN, B, 0, stream>>>(xp, rowp, deg, csr, dinv, W1, b1, W2, t2p);
    k_g2    <<<(int)((N * 32 + B - 1) / B), B, 0, stream>>>(t2p, rowp, deg, csr, agg2);
    k_dense2<<<gN, B, 0, stream>>>(agg2, dinv, b2, W3, t3p);
    k_g3    <<<(int)((N * 16 + B - 1) / B), B, 0, stream>>>(t3p, rowp, deg, csr, agg3);
    k_pool  <<<gN, B, 0, stream>>>(agg3, dinv, b3, Wl, batch, gsum, gcnt);
    k_head  <<<(N_GRAPHS + B - 1) / B, B, 0, stream>>>(gsum, gcnt, bl, out);
}